// Round 10
// baseline (775.377 us; speedup 1.0000x reference)
//
#include <hip/hip_runtime.h>
#include <hip/hip_bf16.h>

#define EPSF 1e-5f
#define BB 2
#define CC 3
#define HH 48
#define WW 48
#define SS 2304
#define DD 64
#define NHH 8
#define FFF 2048
#define NLL 8
#define KS 21
#define PP 441
#define NROW (BB*SS)      // 4608
#define KSPLIT 4
#define KB (SS/KSPLIT)    // 576
#define FFSPLIT 8

typedef __attribute__((ext_vector_type(8))) short s8v;
typedef __attribute__((ext_vector_type(4))) float f4v;
typedef unsigned short ushort_t;

__device__ __forceinline__ ushort_t f2bf(float f) {
  unsigned u = __float_as_uint(f);
  u += 0x7FFFu + ((u >> 16) & 1u);          // round-to-nearest-even
  return (ushort_t)(u >> 16);
}
__device__ __forceinline__ float bf2f(ushort_t h) {
  return __uint_as_float(((unsigned)h) << 16);
}

// ---------------- conv3x3 + batchnorm + relu -> y[b,s,d] ----------------
__global__ __launch_bounds__(256) void k_conv(const float* __restrict__ x,
    const float* __restrict__ cw, const float* __restrict__ cb,
    const float* __restrict__ bng, const float* __restrict__ bnb,
    const float* __restrict__ bnm, const float* __restrict__ bnv,
    float* __restrict__ y)
{
  int tid = blockIdx.x * 256 + threadIdx.x;      // B*S*64 = 294912 threads
  int d = tid & 63;
  int s = (tid >> 6) % SS;
  int b = tid / (SS * 64);
  int h = s / WW, w = s % WW;
  float acc = cb[d];
  #pragma unroll
  for (int c = 0; c < 3; ++c) {
    #pragma unroll
    for (int kh = 0; kh < 3; ++kh) {
      int ih = h + kh - 1;
      if (ih < 0 || ih >= HH) continue;
      #pragma unroll
      for (int kw = 0; kw < 3; ++kw) {
        int iw = w + kw - 1;
        if (iw < 0 || iw >= WW) continue;
        acc = fmaf(x[((b*3 + c)*HH + ih)*WW + iw],
                   cw[((d*3 + c)*3 + kh)*3 + kw], acc);
      }
    }
  }
  acc = (acc - bnm[d]) * rsqrtf(bnv[d] + EPSF) * bng[d] + bnb[d];
  acc = fmaxf(acc, 0.f);
  y[(size_t)(b*SS + s)*DD + d] = acc;
}

// ---- split w1 AND w2 fp32 -> bf16 hi/lo pairs in one dispatch ----
__global__ __launch_bounds__(256) void k_split2(const float* __restrict__ w1,
    const float* __restrict__ w2,
    ushort_t* __restrict__ w1h, ushort_t* __restrict__ w1l,
    ushort_t* __restrict__ w2h, ushort_t* __restrict__ w2l)
{
  const int n = NLL * FFF * DD;
  int i = blockIdx.x * 256 + threadIdx.x;
  if (i < n) {
    float v = w1[i];
    ushort_t h = f2bf(v);
    w1h[i] = h;
    w1l[i] = f2bf(v - bf2f(h));
  } else if (i < 2 * n) {
    int j = i - n;
    float v = w2[j];
    ushort_t h = f2bf(v);
    w2h[j] = h;
    w2l[j] = f2bf(v - bf2f(h));
  }
}

// --- 32-row GEMM (K=64) with optional fused FF-reduce + LN2 prologue ---
// pff!=null: As <- LN2(Ain + b2 + sum_sp pff) (bit-identical to k_ffred);
// LN2 output written to ywr (DIFFERENT buffer than Ain -- no cross-block race)
// by j0==0 blocks. pff==null: As <- Ain.
// J==192 (qkv dispatches): output scattered to head-major layout
// [plane(q,k,v)][b][head][s][8] so k_attn's staging reads are coalesced.
__global__ __launch_bounds__(256) void k_gemm32f(const float* __restrict__ A,
    const float* __restrict__ Wt, const float* __restrict__ bias,
    float* __restrict__ out, int J,
    const float* __restrict__ pff, const float* __restrict__ b2,
    const float* __restrict__ g, const float* __restrict__ bb,
    float* __restrict__ ywr)
{
  __shared__ float As[64][36];   // As[k][m], m in 0..31
  __shared__ float Ws[64][68];   // Ws[k][j]
  int tid = threadIdx.x;
  int m0 = blockIdx.x * 32;
  int j0 = blockIdx.y * 64;
  int tx = tid & 15, ty = tid >> 4;
  #pragma unroll
  for (int i = 0; i < 16; ++i) {
    int idx = tid + i * 256;
    int j = idx >> 6, k = idx & 63;
    int jj = j0 + j;
    Ws[k][j] = (jj < J) ? Wt[(size_t)jj * DD + k] : 0.f;
  }
  if (pff) {
    int w = tid >> 6, lane = tid & 63;
    for (int rr = 0; rr < 8; ++rr) {
      int r32 = w * 8 + rr;
      int m = m0 + r32;
      float f = b2[lane];
      #pragma unroll
      for (int sp = 0; sp < FFSPLIT; ++sp)
        f += pff[((size_t)sp * NROW + m) * DD + lane];
      float z = A[(size_t)m * DD + lane] + f;
      float s = z;
      #pragma unroll
      for (int off = 32; off; off >>= 1) s += __shfl_xor(s, off);
      float mean = s * 0.015625f;
      float dz = z - mean;
      float sq = dz * dz;
      #pragma unroll
      for (int off = 32; off; off >>= 1) sq += __shfl_xor(sq, off);
      float var = sq * 0.015625f;
      float val = dz * rsqrtf(var + EPSF) * g[lane] + bb[lane];
      As[lane][r32] = val;
      if (j0 == 0) ywr[(size_t)m * DD + lane] = val;
    }
  } else {
    #pragma unroll
    for (int i = 0; i < 8; ++i) {
      int idx = tid + i * 256;
      int m = idx >> 6, k = idx & 63;
      As[k][m] = A[(size_t)(m0 + m) * DD + k];
    }
  }
  __syncthreads();
  float acc[2][4] = {};
  #pragma unroll 8
  for (int k = 0; k < 64; ++k) {
    float2 af = *(const float2*)&As[k][ty * 2];
    float4 wf = *(const float4*)&Ws[k][tx * 4];
    float a[2] = {af.x, af.y};
    float w[4] = {wf.x, wf.y, wf.z, wf.w};
    #pragma unroll
    for (int i = 0; i < 2; ++i)
      #pragma unroll
      for (int j = 0; j < 4; ++j)
        acc[i][j] = fmaf(a[i], w[j], acc[i][j]);
  }
  if (J == 192) {
    // head-major scatter: jj0 = j0 + tx*4 is 4-aligned -> stays within one
    // (plane, head) group of 8; one float4 store per (i).
    int jj0 = j0 + tx * 4;
    int plane = jj0 >> 6, hh = (jj0 >> 3) & 7, d0 = jj0 & 7;   // d0 in {0,4}
    float4 bi = *(const float4*)&bias[jj0];
    #pragma unroll
    for (int i = 0; i < 2; ++i) {
      int m = m0 + ty * 2 + i;
      int bb_ = m / SS, s = m - bb_ * SS;
      float4 o = make_float4(acc[i][0] + bi.x, acc[i][1] + bi.y,
                             acc[i][2] + bi.z, acc[i][3] + bi.w);
      *(float4*)&out[(((size_t)plane * BB + bb_) * NHH + hh) * (SS * 8)
                     + (size_t)s * 8 + d0] = o;
    }
  } else {
    #pragma unroll
    for (int i = 0; i < 2; ++i) {
      int m = m0 + ty * 2 + i;
      #pragma unroll
      for (int j = 0; j < 4; ++j) {
        int jj = j0 + tx * 4 + j;
        if (jj >= J) continue;
        out[(size_t)m * J + jj] = acc[i][j] + bias[jj];
      }
    }
  }
}

// ---- standalone FF-reduce + LN2 (used before the final logits GEMM) ----
// yout <- LN2(A + b2 + sum_sp pff); bit-identical math to k_gemm32f prologue.
__global__ __launch_bounds__(256) void k_ffred(const float* __restrict__ A,
    const float* __restrict__ pff, const float* __restrict__ b2,
    const float* __restrict__ g, const float* __restrict__ bb,
    float* __restrict__ yout)
{
  int m = blockIdx.x * 4 + (threadIdx.x >> 6);
  int lane = threadIdx.x & 63;
  float f = b2[lane];
  #pragma unroll
  for (int sp = 0; sp < FFSPLIT; ++sp)
    f += pff[((size_t)sp * NROW + m) * DD + lane];
  float z = A[(size_t)m * DD + lane] + f;
  float s = z;
  #pragma unroll
  for (int off = 32; off; off >>= 1) s += __shfl_xor(s, off);
  float mean = s * 0.015625f;
  float dz = z - mean;
  float sq = dz * dz;
  #pragma unroll
  for (int off = 32; off; off >>= 1) sq += __shfl_xor(sq, off);
  float var = sq * 0.015625f;
  yout[(size_t)m * DD + lane] = dz * rsqrtf(var + EPSF) * g[lane] + bb[lane];
}

// -- fused: attn split-combine + out-proj GEMM + residual + LN1 (+ y hi/lo) --
// y is read-modify-written in place: each block owns its 32 rows exclusively.
__global__ __launch_bounds__(256) void k_oproj_ln(const float* __restrict__ pl,
    const float* __restrict__ pacc,
    const float* __restrict__ Wt, const float* __restrict__ bias,
    float* __restrict__ y, const float* __restrict__ g, const float* __restrict__ bb,
    ushort_t* __restrict__ yh, ushort_t* __restrict__ yl)
{
  __shared__ float As[64][36];   // As[k][m] = o[m0+m][k]
  __shared__ float Ws[64][68];   // Ws[k][j] = Wt[j][k]
  int tid = threadIdx.x;
  int m0 = blockIdx.x * 32;
  int b = m0 / SS;               // all 32 rows share b (SS % 32 == 0)
  int tx = tid & 15, ty = tid >> 4;

  {
    int r32 = tid & 31, hh = tid >> 5;
    int qi = (m0 % SS) + r32;
    float L = 0.f, a[8] = {};
    #pragma unroll
    for (int sp = 0; sp < KSPLIT; ++sp) {
      size_t pidx = ((size_t)sp * 16 + b * 8 + hh) * SS + qi;
      L += pl[pidx];
      const float4* pa = (const float4*)(pacc + pidx * 8);
      float4 a0 = pa[0], a1 = pa[1];
      a[0] += a0.x; a[1] += a0.y; a[2] += a0.z; a[3] += a0.w;
      a[4] += a1.x; a[5] += a1.y; a[6] += a1.z; a[7] += a1.w;
    }
    float inv = 1.f / L;
    #pragma unroll
    for (int d = 0; d < 8; ++d) As[hh * 8 + d][r32] = a[d] * inv;
  }
  #pragma unroll
  for (int i = 0; i < 16; ++i) {
    int idx = tid + i * 256;
    int j = idx >> 6, k = idx & 63;
    Ws[k][j] = Wt[(size_t)j * DD + k];
  }
  __syncthreads();

  float acc[2][4] = {};
  #pragma unroll 8
  for (int k = 0; k < 64; ++k) {
    float2 af = *(const float2*)&As[k][ty * 2];
    float4 wf = *(const float4*)&Ws[k][tx * 4];
    float a[2] = {af.x, af.y};
    float w[4] = {wf.x, wf.y, wf.z, wf.w};
    #pragma unroll
    for (int i = 0; i < 2; ++i)
      #pragma unroll
      for (int j = 0; j < 4; ++j)
        acc[i][j] = fmaf(a[i], w[j], acc[i][j]);
  }
  float4 gv = *(const float4*)&g[tx * 4];
  float4 bv = *(const float4*)&bb[tx * 4];
  float4 biv = *(const float4*)&bias[tx * 4];
  float gg[4] = {gv.x, gv.y, gv.z, gv.w};
  float bbv[4] = {bv.x, bv.y, bv.z, bv.w};
  float bi[4] = {biv.x, biv.y, biv.z, biv.w};
  #pragma unroll
  for (int i = 0; i < 2; ++i) {
    int m = m0 + ty * 2 + i;
    float4 yv = *(const float4*)&y[(size_t)m * DD + tx * 4];
    float yr[4] = {yv.x, yv.y, yv.z, yv.w};
    float z[4], s = 0.f, ss = 0.f;
    #pragma unroll
    for (int j = 0; j < 4; ++j) {
      float v = acc[i][j] + bi[j] + yr[j];
      z[j] = v; s += v; ss = fmaf(v, v, ss);
    }
    #pragma unroll
    for (int off = 1; off < 16; off <<= 1) {
      s  += __shfl_xor(s, off);
      ss += __shfl_xor(ss, off);
    }
    float mean = s * 0.015625f;
    float var = ss * 0.015625f - mean * mean;
    float inv = rsqrtf(var + EPSF);
    float ov[4];
    #pragma unroll
    for (int j = 0; j < 4; ++j)
      ov[j] = (z[j] - mean) * inv * gg[j] + bbv[j];
    *(float4*)&y[(size_t)m * DD + tx * 4] = make_float4(ov[0], ov[1], ov[2], ov[3]);
    size_t yb = (size_t)m * DD + tx * 4;
    #pragma unroll
    for (int j = 0; j < 4; ++j) {
      ushort_t h = f2bf(ov[j]);
      yh[yb + j] = h;
      yl[yb + j] = f2bf(ov[j] - bf2f(h));
    }
  }
}

// ---- fused FF via split-bf16 MFMA, zero-redundancy loads ----
// 32-ROW m-tiles (was 64): grid (8,144)=1152 blocks (4.5/CU issued, 8/CU
// resident at 9.2 KB LDS) -- doubles TLP to hide the 8-barrier phase chain.
// Per-output math identical to the 64-row version (same fragments, same
// 6-MFMA split sequence, same K order) -> bit-identical results.
__global__ __launch_bounds__(256) void k_ff(const ushort_t* __restrict__ yh,
    const ushort_t* __restrict__ yl,
    const ushort_t* __restrict__ w1h, const ushort_t* __restrict__ w1l,
    const float* __restrict__ b1,
    const ushort_t* __restrict__ w2h, const ushort_t* __restrict__ w2l,
    float* __restrict__ pff)
{
  __shared__ ushort_t Hh[32][72];   // H[m][ff] hi bf16, stride 72 (16B align)
  __shared__ ushort_t Hl[32][72];   // H[m][ff] lo bf16
  int tid = threadIdx.x;
  int w = tid >> 6, lane = tid & 63;
  int laneR = lane & 15, laneQ = lane >> 4;
  int split = blockIdx.x;
  int m0 = blockIdx.y * 32;

  s8v a1h[2][2], a1l[2][2];
  #pragma unroll
  for (int t = 0; t < 2; ++t) {
    size_t yb = (size_t)(m0 + t * 16 + laneR) * DD + laneQ * 8;
    a1h[t][0] = *(const s8v*)(yh + yb);
    a1h[t][1] = *(const s8v*)(yh + yb + 32);
    a1l[t][0] = *(const s8v*)(yl + yb);
    a1l[t][1] = *(const s8v*)(yl + yb + 32);
  }

  f4v acc2[2];
  #pragma unroll
  for (int t = 0; t < 2; ++t) acc2[t] = (f4v){0.f, 0.f, 0.f, 0.f};

  for (int c = 0; c < FFF / FFSPLIT / 64; ++c) {
    int ff0 = split * (FFF / FFSPLIT) + c * 64;
    size_t wb1 = (size_t)(ff0 + w * 16 + laneR) * DD + laneQ * 8;
    s8v b0h = *(const s8v*)(w1h + wb1);
    s8v b0l = *(const s8v*)(w1l + wb1);
    s8v b1h_ = *(const s8v*)(w1h + wb1 + 32);
    s8v b1l_ = *(const s8v*)(w1l + wb1 + 32);
    size_t wb2 = (size_t)(w * 16 + laneR) * FFF + ff0 + laneQ * 8;
    s8v c0h = *(const s8v*)(w2h + wb2);
    s8v c0l = *(const s8v*)(w2l + wb2);
    s8v c1h = *(const s8v*)(w2h + wb2 + 32);
    s8v c1l = *(const s8v*)(w2l + wb2 + 32);
    float bj = b1[ff0 + w * 16 + laneR];

    if (c) __syncthreads();
    #pragma unroll
    for (int t = 0; t < 2; ++t) {
      f4v acc = (f4v){0.f, 0.f, 0.f, 0.f};
      acc = __builtin_amdgcn_mfma_f32_16x16x32_bf16(a1h[t][0], b0h, acc, 0, 0, 0);
      acc = __builtin_amdgcn_mfma_f32_16x16x32_bf16(a1h[t][0], b0l, acc, 0, 0, 0);
      acc = __builtin_amdgcn_mfma_f32_16x16x32_bf16(a1l[t][0], b0h, acc, 0, 0, 0);
      acc = __builtin_amdgcn_mfma_f32_16x16x32_bf16(a1h[t][1], b1h_, acc, 0, 0, 0);
      acc = __builtin_amdgcn_mfma_f32_16x16x32_bf16(a1h[t][1], b1l_, acc, 0, 0, 0);
      acc = __builtin_amdgcn_mfma_f32_16x16x32_bf16(a1l[t][1], b1h_, acc, 0, 0, 0);
      #pragma unroll
      for (int r = 0; r < 4; ++r) {
        float v = fmaxf(acc[r] + bj, 0.f);
        ushort_t hb = f2bf(v);
        int rr = t * 16 + laneQ * 4 + r, cc = w * 16 + laneR;
        Hh[rr][cc] = hb;
        Hl[rr][cc] = f2bf(v - bf2f(hb));
      }
    }
    __syncthreads();
    #pragma unroll
    for (int t = 0; t < 2; ++t) {
      s8v a2h[2], a2l[2];
      #pragma unroll
      for (int half = 0; half < 2; ++half) {
        a2h[half] = *(const s8v*)&Hh[t * 16 + laneR][half * 32 + laneQ * 8];
        a2l[half] = *(const s8v*)&Hl[t * 16 + laneR][half * 32 + laneQ * 8];
      }
      acc2[t] = __builtin_amdgcn_mfma_f32_16x16x32_bf16(a2h[0], c0h, acc2[t], 0, 0, 0);
      acc2[t] = __builtin_amdgcn_mfma_f32_16x16x32_bf16(a2h[0], c0l, acc2[t], 0, 0, 0);
      acc2[t] = __builtin_amdgcn_mfma_f32_16x16x32_bf16(a2l[0], c0h, acc2[t], 0, 0, 0);
      acc2[t] = __builtin_amdgcn_mfma_f32_16x16x32_bf16(a2h[1], c1h, acc2[t], 0, 0, 0);
      acc2[t] = __builtin_amdgcn_mfma_f32_16x16x32_bf16(a2h[1], c1l, acc2[t], 0, 0, 0);
      acc2[t] = __builtin_amdgcn_mfma_f32_16x16x32_bf16(a2l[1], c1h, acc2[t], 0, 0, 0);
    }
  }
  #pragma unroll
  for (int t = 0; t < 2; ++t) {
    #pragma unroll
    for (int r = 0; r < 4; ++r) {
      int m = m0 + t * 16 + laneQ * 4 + r;
      pff[((size_t)split * NROW + m) * DD + w * 16 + laneR] = acc2[t][r];
    }
  }
}

// ---- MFMA flash attention (split-K): QK^T and PV on matrix cores ----
// Swapped QK^T (lane-local q-row) + in-register P->PV handoff (k-bijection
// applied to both PV operands). qkv is HEAD-MAJOR [plane][b][head][s][8]:
// staging reads are fully coalesced (consecutive rows = consecutive 32B).
__global__ __launch_bounds__(256) void k_attn(const float* __restrict__ qkv,
    float* __restrict__ pl, float* __restrict__ pacc)
{
  __shared__ ushort_t Kb[KB][8];       // bf16 K rows: Kb[key][d]
  __shared__ ushort_t Vt[8][KB + 8];   // bf16 V transposed: Vt[d][key]
  int bh = blockIdx.x; int b = bh >> 3; int hh = bh & 7;
  int qt = blockIdx.y, sp = blockIdx.z;
  int tid = threadIdx.x;

  const float* kbase = qkv + (((size_t)BB + b) * NHH + hh) * (SS * 8)
                           + (size_t)(sp * KB) * 8;
  const float* vbase = qkv + (((size_t)2 * BB + b) * NHH + hh) * (SS * 8)
                           + (size_t)(sp * KB) * 8;
  for (int r = tid; r < KB; r += 256) {
    const float* ksrc = kbase + (size_t)r * 8;
    float4 k0 = *(const float4*)ksrc;
    float4 k1 = *(const float4*)(ksrc + 4);
    ushort_t kh[8] = {f2bf(k0.x), f2bf(k0.y), f2bf(k0.z), f2bf(k0.w),
                      f2bf(k1.x), f2bf(k1.y), f2bf(k1.z), f2bf(k1.w)};
    *(uint4*)&Kb[r][0] = *(const uint4*)kh;
    const float* vsrc = vbase + (size_t)r * 8;
    float4 v0 = *(const float4*)vsrc;
    float4 v1 = *(const float4*)(vsrc + 4);
    Vt[0][r] = f2bf(v0.x); Vt[1][r] = f2bf(v0.y);
    Vt[2][r] = f2bf(v0.z); Vt[3][r] = f2bf(v0.w);
    Vt[4][r] = f2bf(v1.x); Vt[5][r] = f2bf(v1.y);
    Vt[6][r] = f2bf(v1.z); Vt[7][r] = f2bf(v1.w);
  }
  __syncthreads();

  int w = tid >> 6, lane = tid & 63;
  int n = lane & 15, quad = lane >> 4;
  const float scq = 0.51006972783f;    // log2(e) / sqrt(8)
  const s8v zero8 = (s8v){0, 0, 0, 0, 0, 0, 0, 0};
  const f4v zero4 = (f4v){0.f, 0.f, 0.f, 0.f};

  s8v aq = zero8;
  if (quad == 0) {
    const float* qp = qkv + ((size_t)b * NHH + hh) * (SS * 8)
                          + (size_t)(qt * 64 + w * 16 + n) * 8;
    float4 q0 = *(const float4*)qp;
    float4 q1 = *(const float4*)(qp + 4);
    aq[0] = (short)f2bf(q0.x * scq); aq[1] = (short)f2bf(q0.y * scq);
    aq[2] = (short)f2bf(q0.z * scq); aq[3] = (short)f2bf(q0.w * scq);
    aq[4] = (short)f2bf(q1.x * scq); aq[5] = (short)f2bf(q1.y * scq);
    aq[6] = (short)f2bf(q1.z * scq); aq[7] = (short)f2bf(q1.w * scq);
  }

  f4v accO = zero4;
  float l = 0.f;

  #pragma unroll 2
  for (int ck = 0; ck < KB; ck += 32) {
    s8v ak0 = zero8, ak1 = zero8;
    if (quad == 0) {
      ak0 = *(const s8v*)&Kb[ck + n][0];
      ak1 = *(const s8v*)&Kb[ck + 16 + n][0];
    }
    // swapped operands: S[key=ck+4q+r][qrow=n] in c0, S[key=ck+16+4q+r] in c1
    f4v c0 = __builtin_amdgcn_mfma_f32_16x16x32_bf16(ak0, aq, zero4, 0, 0, 0);
    f4v c1 = __builtin_amdgcn_mfma_f32_16x16x32_bf16(ak1, aq, zero4, 0, 0, 0);
    float p0[4], p1[4];
    #pragma unroll
    for (int r = 0; r < 4; ++r) { p0[r] = exp2f(c0[r]); l += p0[r]; }
    #pragma unroll
    for (int r = 0; r < 4; ++r) { p1[r] = exp2f(c1[r]); l += p1[r]; }
    unsigned u0, u1, v0, v1;
    asm("v_cvt_pk_bf16_f32 %0, %1, %2" : "=v"(u0) : "v"(p0[0]), "v"(p0[1]));
    asm("v_cvt_pk_bf16_f32 %0, %1, %2" : "=v"(u1) : "v"(p0[2]), "v"(p0[3]));
    asm("v_cvt_pk_bf16_f32 %0, %1, %2" : "=v"(v0) : "v"(p1[0]), "v"(p1[1]));
    asm("v_cvt_pk_bf16_f32 %0, %1, %2" : "=v"(v1) : "v"(p1[2]), "v"(p1[3]));
    // A-fragment: this lane's own P values, keys {4q..4q+3, 16+4q..16+4q+3}
    union { uint4 u; s8v s; } ca;
    ca.u = make_uint4(u0, u1, v0, v1);
    // B-fragment: V at the SAME permuted key order (two b64 reads, 8B-aligned)
    const ushort_t* vp = &Vt[n & 7][ck + quad * 4];
    uint2 bv0 = *(const uint2*)vp;
    uint2 bv1 = *(const uint2*)(vp + 16);
    union { uint4 u; s8v s; } cb;
    cb.u = make_uint4(bv0.x, bv0.y, bv1.x, bv1.y);
    accO = __builtin_amdgcn_mfma_f32_16x16x32_bf16(ca.s, cb.s, accO, 0, 0, 0);
  }

  // l[q=n] is per-lane: reduce across the 4 quads
  l += __shfl_xor(l, 16);
  l += __shfl_xor(l, 32);
  int qbase0 = qt * 64 + w * 16;
  size_t pbase0 = ((size_t)sp * 16 + bh) * SS + qbase0;
  if (quad == 0) pl[pbase0 + n] = l;
  size_t pbase = pbase0 + quad * 4;
  if (n < 8) {
    #pragma unroll
    for (int r = 0; r < 4; ++r)
      pacc[(pbase + r) * 8 + n] = accO[r];
  }
}

// ---- fused: softmax over 441 logits -> kernel_out + 3-channel gather ----
__global__ __launch_bounds__(256) void k_softgather(const float* __restrict__ logits,
    const float* __restrict__ x, float* __restrict__ kout, float* __restrict__ out)
{
  __shared__ float red[8];
  __shared__ float gred[3][4];
  int row = blockIdx.x;               // b*S + s
  int b = row / SS, s = row % SS;
  int h = s / WW, w = s % WW;
  const float* lp = logits + (size_t)row * PP;
  int t = threadIdx.x;
  float v0 = (t < PP) ? lp[t] : -1e30f;
  float v1 = (t + 256 < PP) ? lp[t + 256] : -1e30f;
  float mx = fmaxf(v0, v1);
  #pragma unroll
  for (int off = 32; off; off >>= 1) mx = fmaxf(mx, __shfl_xor(mx, off));
  if ((t & 63) == 0) red[t >> 6] = mx;
  __syncthreads();
  mx = fmaxf(fmaxf(red[0], red[1]), fmaxf(red[2], red[3]));
  float e0 = (t < PP) ? __expf(v0 - mx) : 0.f;
  float e1 = (t + 256 < PP) ? __expf(v1 - mx) : 0.f;
  float sm = e0 + e1;
  #pragma unroll
  for (int off = 32; off; off >>= 1) sm += __shfl_xor(sm, off);
  if ((t & 63) == 0) red[4 + (t >> 6)] = sm;
  __syncthreads();
  float inv = 1.f / (red[4] + red[5] + red[6] + red[7]);
  float p0 = e0 * inv, p1 = e1 * inv;
  if (t < PP)       kout[(size_t)(b * PP + t) * SS + s] = p0;
  if (t + 256 < PP) kout[(size_t)(b * PP + t + 256) * SS + s] = p1;

  int kr0 = t / KS, kc0 = t - kr0 * KS;
  int t1 = t + 256;
  int kr1 = t1 / KS, kc1 = t1 - kr1 * KS;
  int ih0 = h + kr0 - 10; ih0 = (ih0 < 0) ? -ih0 : (ih0 > 47 ? 94 - ih0 : ih0);
  int iw0 = w + kc0 - 10; iw0 = (iw0 < 0) ? -iw0 : (iw0 > 47 ? 94 - iw0 : iw0);
  int ih1 = h + kr1 - 10; ih1 = (ih1 < 0) ? -ih1 : (ih1 > 47 ? 94 - ih1 : ih1);
  int iw1 = w + kc1 - 10; iw1 = (iw1 < 0) ? -iw1 : (iw1 > 47 ? 94 - iw1 : iw1);
  float acc[3];
  #pragma unroll
  for (int c = 0; c < 3; ++c) {
    const float* xb = x + (size_t)(b * CC + c) * HH * WW;
    float a = 0.f;
    if (t < PP)  a = p0 * xb[ih0 * WW + iw0];
    if (t1 < PP) a = fmaf(p1, xb[ih1 * WW + iw1], a);
    acc[c] = a;
  }
  #pragma unroll
  for (int c = 0; c < 3; ++c) {
    #pragma unroll
    for (int off = 32; off; off >>= 1) acc[c] += __shfl_xor(acc[c], off);
  }
  if ((t & 63) == 0) {
    gred[0][t >> 6] = acc[0];
    gred[1][t >> 6] = acc[1];
    gred[2][t >> 6] = acc[2];
  }
  __syncthreads();
  if (t < 3) {
    float r = gred[t][0] + gred[t][1] + gred[t][2] + gred[t][3];
    out[((size_t)(b * CC + t) * HH + h) * WW + w] = r;
  }
}

extern "C" void kernel_launch(void* const* d_in, const int* in_sizes, int n_in,
                              void* d_out, int out_size, void* d_ws, size_t ws_size,
                              hipStream_t stream)
{
  (void)in_sizes; (void)n_in; (void)out_size; (void)ws_size;
  const float* x       = (const float*)d_in[0];
  const float* conv1_w = (const float*)d_in[1];
  const float* conv1_b = (const float*)d_in[2];
  const float* bn_g    = (const float*)d_in[3];
  const float* bn_b    = (const float*)d_in[4];
  const float* bn_m    = (const float*)d_in[5];
  const float* bn_v    = (const float*)d_in[6];
  const float* w_in    = (const float*)d_in[7];
  const float* b_in    = (const float*)d_in[8];
  const float* w_out   = (const float*)d_in[9];
  const float* b_out   = (const float*)d_in[10];
  const float* w1      = (const float*)d_in[11];
  const float* b1      = (const float*)d_in[12];
  const float* w2      = (const float*)d_in[13];
  const float* b2      = (const float*)d_in[14];
  const float* ln1g    = (const float*)d_in[15];
  const float* ln1b    = (const float*)d_in[16];
  const float* ln2g    = (const float*)d_in[17];
  const float* ln2b    = (const float*)d_in[18];
  const float* lw      = (const float*)d_in[19];
  const float* lb      = (const float*)d_in[20];

  // workspace: ~42.8 MiB (identical layout to round-9 passing kernel)
  float* yA   = (float*)d_ws;        // 294912 (layer y, even layers)
  float* qkv  = yA + 294912;         // 884736 (head-major [plane][b][h][s][8])
  float* yB   = qkv + 884736;        // 294912 (layer y, odd layers)
  float* sc   = yB + 294912;         // union region: 4718592 floats
  float* pacc = sc;                  // attn acc partials: 4*16*2304*8 = 1179648
  float* pff  = sc;                  // FF partials: 8*4608*64 = 2359296
  float* pl   = sc + 4718592;        // attn l partials: 4*16*2304 = 147456
  ushort_t* yh  = (ushort_t*)(pl + 589824);
  ushort_t* yl  = (ushort_t*)(pl + 589824 + 147456);
  ushort_t* w1h = (ushort_t*)(pl + 589824 + 294912);
  ushort_t* w1l = (ushort_t*)(pl + 589824 + 294912 + 524288);
  ushort_t* w2h = (ushort_t*)(pl + 589824 + 294912 + 1048576);
  ushort_t* w2l = (ushort_t*)(pl + 589824 + 294912 + 1572864);
  float* logits = pl + 589824 + 294912 + 2097152;   // 2032128 floats

  float* ybuf[2] = {yA, yB};

  float* out0 = (float*)d_out;
  float* kout = out0 + (size_t)BB * CC * HH * WW;

  k_split2<<<8192, 256, 0, stream>>>(w1, w2, w1h, w1l, w2h, w2l);
  k_conv<<<1152, 256, 0, stream>>>(x, conv1_w, conv1_b, bn_g, bn_b, bn_m, bn_v, yA);

  for (int l = 0; l < NLL; ++l) {
    float* ycur = ybuf[l & 1];
    if (l == 0)
      k_gemm32f<<<dim3(144, 3), 256, 0, stream>>>(yA, w_in, b_in, qkv, 192,
          nullptr, nullptr, nullptr, nullptr, yA);
    else
      // reads prev-layer y, writes LN2 output into ycur (different buffer -> no race)
      k_gemm32f<<<dim3(144, 3), 256, 0, stream>>>(ybuf[(l - 1) & 1],
          w_in + (size_t)l * 192 * 64, b_in + l * 192, qkv, 192,
          pff, b2 + (l - 1) * DD, ln2g + (l - 1) * 64, ln2b + (l - 1) * 64, ycur);
    k_attn<<<dim3(16, 36, KSPLIT), 256, 0, stream>>>(qkv, pl, pacc);
    k_oproj_ln<<<144, 256, 0, stream>>>(pl, pacc, w_out + (size_t)l * 64 * 64,
        b_out + l * 64, ycur, ln1g + l * 64, ln1b + l * 64, yh, yl);
    k_ff<<<dim3(FFSPLIT, 144), 256, 0, stream>>>(yh, yl,
        w1h + (size_t)l * FFF * DD, w1l + (size_t)l * FFF * DD, b1 + (size_t)l * FFF,
        w2h + (size_t)l * FFF * DD, w2l + (size_t)l * FFF * DD, pff);
  }

  // final: reduce layer-7 FF + LN2 once, then logits GEMM without
  // the 7x-redundant fused prologue
  k_ffred<<<1152, 256, 0, stream>>>(ybuf[1], pff, b2 + 7 * DD,
      ln2g + 7 * 64, ln2b + 7 * 64, ybuf[0]);
  k_gemm32f<<<dim3(144, 7), 256, 0, stream>>>(ybuf[0], lw, lb, logits, 441,
      nullptr, nullptr, nullptr, nullptr, ybuf[1]);
  k_softgather<<<NROW, 256, 0, stream>>>(logits, x, kout, out0);
}

// Round 11
// 673.268 us; speedup vs baseline: 1.1517x; 1.1517x over previous
//
#include <hip/hip_runtime.h>
#include <hip/hip_bf16.h>

#define EPSF 1e-5f
#define BB 2
#define CC 3
#define HH 48
#define WW 48
#define SS 2304
#define DD 64
#define NHH 8
#define FFF 2048
#define NLL 8
#define KS 21
#define PP 441
#define NROW (BB*SS)      // 4608
#define KSPLIT 4
#define KB (SS/KSPLIT)    // 576
#define FFSPLIT 8

typedef __attribute__((ext_vector_type(8))) short s8v;
typedef __attribute__((ext_vector_type(4))) float f4v;
typedef unsigned short ushort_t;

__device__ __forceinline__ ushort_t f2bf(float f) {
  unsigned u = __float_as_uint(f);
  u += 0x7FFFu + ((u >> 16) & 1u);          // round-to-nearest-even
  return (ushort_t)(u >> 16);
}
__device__ __forceinline__ float bf2f(ushort_t h) {
  return __uint_as_float(((unsigned)h) << 16);
}

// ---------------- conv3x3 + batchnorm + relu -> y[b,s,d] ----------------
__global__ __launch_bounds__(256) void k_conv(const float* __restrict__ x,
    const float* __restrict__ cw, const float* __restrict__ cb,
    const float* __restrict__ bng, const float* __restrict__ bnb,
    const float* __restrict__ bnm, const float* __restrict__ bnv,
    float* __restrict__ y)
{
  int tid = blockIdx.x * 256 + threadIdx.x;      // B*S*64 = 294912 threads
  int d = tid & 63;
  int s = (tid >> 6) % SS;
  int b = tid / (SS * 64);
  int h = s / WW, w = s % WW;
  float acc = cb[d];
  #pragma unroll
  for (int c = 0; c < 3; ++c) {
    #pragma unroll
    for (int kh = 0; kh < 3; ++kh) {
      int ih = h + kh - 1;
      if (ih < 0 || ih >= HH) continue;
      #pragma unroll
      for (int kw = 0; kw < 3; ++kw) {
        int iw = w + kw - 1;
        if (iw < 0 || iw >= WW) continue;
        acc = fmaf(x[((b*3 + c)*HH + ih)*WW + iw],
                   cw[((d*3 + c)*3 + kh)*3 + kw], acc);
      }
    }
  }
  acc = (acc - bnm[d]) * rsqrtf(bnv[d] + EPSF) * bng[d] + bnb[d];
  acc = fmaxf(acc, 0.f);
  y[(size_t)(b*SS + s)*DD + d] = acc;
}

// ---- split w1 AND w2 fp32 -> bf16 hi/lo pairs in one dispatch ----
__global__ __launch_bounds__(256) void k_split2(const float* __restrict__ w1,
    const float* __restrict__ w2,
    ushort_t* __restrict__ w1h, ushort_t* __restrict__ w1l,
    ushort_t* __restrict__ w2h, ushort_t* __restrict__ w2l)
{
  const int n = NLL * FFF * DD;
  int i = blockIdx.x * 256 + threadIdx.x;
  if (i < n) {
    float v = w1[i];
    ushort_t h = f2bf(v);
    w1h[i] = h;
    w1l[i] = f2bf(v - bf2f(h));
  } else if (i < 2 * n) {
    int j = i - n;
    float v = w2[j];
    ushort_t h = f2bf(v);
    w2h[j] = h;
    w2l[j] = f2bf(v - bf2f(h));
  }
}

// --- 32-row GEMM (K=64) with optional fused FF-reduce + LN2 prologue ---
// pff!=null: As <- LN2(Ain + b2 + sum_sp pff) (bit-identical to k_ffred);
// LN2 output written to ywr (DIFFERENT buffer than Ain -- no cross-block race)
// by j0==0 blocks. pff==null: As <- Ain.
// J==192 (qkv dispatches): output scattered to head-major layout
// [plane(q,k,v)][b][head][s][8] so k_attn's staging reads are coalesced.
__global__ __launch_bounds__(256) void k_gemm32f(const float* __restrict__ A,
    const float* __restrict__ Wt, const float* __restrict__ bias,
    float* __restrict__ out, int J,
    const float* __restrict__ pff, const float* __restrict__ b2,
    const float* __restrict__ g, const float* __restrict__ bb,
    float* __restrict__ ywr)
{
  __shared__ float As[64][36];   // As[k][m], m in 0..31
  __shared__ float Ws[64][68];   // Ws[k][j]
  int tid = threadIdx.x;
  int m0 = blockIdx.x * 32;
  int j0 = blockIdx.y * 64;
  int tx = tid & 15, ty = tid >> 4;
  #pragma unroll
  for (int i = 0; i < 16; ++i) {
    int idx = tid + i * 256;
    int j = idx >> 6, k = idx & 63;
    int jj = j0 + j;
    Ws[k][j] = (jj < J) ? Wt[(size_t)jj * DD + k] : 0.f;
  }
  if (pff) {
    int w = tid >> 6, lane = tid & 63;
    for (int rr = 0; rr < 8; ++rr) {
      int r32 = w * 8 + rr;
      int m = m0 + r32;
      float f = b2[lane];
      #pragma unroll
      for (int sp = 0; sp < FFSPLIT; ++sp)
        f += pff[((size_t)sp * NROW + m) * DD + lane];
      float z = A[(size_t)m * DD + lane] + f;
      float s = z;
      #pragma unroll
      for (int off = 32; off; off >>= 1) s += __shfl_xor(s, off);
      float mean = s * 0.015625f;
      float dz = z - mean;
      float sq = dz * dz;
      #pragma unroll
      for (int off = 32; off; off >>= 1) sq += __shfl_xor(sq, off);
      float var = sq * 0.015625f;
      float val = dz * rsqrtf(var + EPSF) * g[lane] + bb[lane];
      As[lane][r32] = val;
      if (j0 == 0) ywr[(size_t)m * DD + lane] = val;
    }
  } else {
    #pragma unroll
    for (int i = 0; i < 8; ++i) {
      int idx = tid + i * 256;
      int m = idx >> 6, k = idx & 63;
      As[k][m] = A[(size_t)(m0 + m) * DD + k];
    }
  }
  __syncthreads();
  float acc[2][4] = {};
  #pragma unroll 8
  for (int k = 0; k < 64; ++k) {
    float2 af = *(const float2*)&As[k][ty * 2];
    float4 wf = *(const float4*)&Ws[k][tx * 4];
    float a[2] = {af.x, af.y};
    float w[4] = {wf.x, wf.y, wf.z, wf.w};
    #pragma unroll
    for (int i = 0; i < 2; ++i)
      #pragma unroll
      for (int j = 0; j < 4; ++j)
        acc[i][j] = fmaf(a[i], w[j], acc[i][j]);
  }
  if (J == 192) {
    // head-major scatter: jj0 = j0 + tx*4 is 4-aligned -> stays within one
    // (plane, head) group of 8; one float4 store per (i).
    int jj0 = j0 + tx * 4;
    int plane = jj0 >> 6, hh = (jj0 >> 3) & 7, d0 = jj0 & 7;   // d0 in {0,4}
    float4 bi = *(const float4*)&bias[jj0];
    #pragma unroll
    for (int i = 0; i < 2; ++i) {
      int m = m0 + ty * 2 + i;
      int bb_ = m / SS, s = m - bb_ * SS;
      float4 o = make_float4(acc[i][0] + bi.x, acc[i][1] + bi.y,
                             acc[i][2] + bi.z, acc[i][3] + bi.w);
      *(float4*)&out[(((size_t)plane * BB + bb_) * NHH + hh) * (SS * 8)
                     + (size_t)s * 8 + d0] = o;
    }
  } else {
    #pragma unroll
    for (int i = 0; i < 2; ++i) {
      int m = m0 + ty * 2 + i;
      #pragma unroll
      for (int j = 0; j < 4; ++j) {
        int jj = j0 + tx * 4 + j;
        if (jj >= J) continue;
        out[(size_t)m * J + jj] = acc[i][j] + bias[jj];
      }
    }
  }
}

// ---- standalone FF-reduce + LN2 (used before the final logits GEMM) ----
// yout <- LN2(A + b2 + sum_sp pff); bit-identical math to k_gemm32f prologue.
__global__ __launch_bounds__(256) void k_ffred(const float* __restrict__ A,
    const float* __restrict__ pff, const float* __restrict__ b2,
    const float* __restrict__ g, const float* __restrict__ bb,
    float* __restrict__ yout)
{
  int m = blockIdx.x * 4 + (threadIdx.x >> 6);
  int lane = threadIdx.x & 63;
  float f = b2[lane];
  #pragma unroll
  for (int sp = 0; sp < FFSPLIT; ++sp)
    f += pff[((size_t)sp * NROW + m) * DD + lane];
  float z = A[(size_t)m * DD + lane] + f;
  float s = z;
  #pragma unroll
  for (int off = 32; off; off >>= 1) s += __shfl_xor(s, off);
  float mean = s * 0.015625f;
  float dz = z - mean;
  float sq = dz * dz;
  #pragma unroll
  for (int off = 32; off; off >>= 1) sq += __shfl_xor(sq, off);
  float var = sq * 0.015625f;
  yout[(size_t)m * DD + lane] = dz * rsqrtf(var + EPSF) * g[lane] + bb[lane];
}

// -- fused: attn split-combine + out-proj GEMM + residual + LN1 (+ y hi/lo) --
// y is read-modify-written in place: each block owns its 32 rows exclusively.
__global__ __launch_bounds__(256) void k_oproj_ln(const float* __restrict__ pl,
    const float* __restrict__ pacc,
    const float* __restrict__ Wt, const float* __restrict__ bias,
    float* __restrict__ y, const float* __restrict__ g, const float* __restrict__ bb,
    ushort_t* __restrict__ yh, ushort_t* __restrict__ yl)
{
  __shared__ float As[64][36];   // As[k][m] = o[m0+m][k]
  __shared__ float Ws[64][68];   // Ws[k][j] = Wt[j][k]
  int tid = threadIdx.x;
  int m0 = blockIdx.x * 32;
  int b = m0 / SS;               // all 32 rows share b (SS % 32 == 0)
  int tx = tid & 15, ty = tid >> 4;

  {
    int r32 = tid & 31, hh = tid >> 5;
    int qi = (m0 % SS) + r32;
    float L = 0.f, a[8] = {};
    #pragma unroll
    for (int sp = 0; sp < KSPLIT; ++sp) {
      size_t pidx = ((size_t)sp * 16 + b * 8 + hh) * SS + qi;
      L += pl[pidx];
      const float4* pa = (const float4*)(pacc + pidx * 8);
      float4 a0 = pa[0], a1 = pa[1];
      a[0] += a0.x; a[1] += a0.y; a[2] += a0.z; a[3] += a0.w;
      a[4] += a1.x; a[5] += a1.y; a[6] += a1.z; a[7] += a1.w;
    }
    float inv = 1.f / L;
    #pragma unroll
    for (int d = 0; d < 8; ++d) As[hh * 8 + d][r32] = a[d] * inv;
  }
  #pragma unroll
  for (int i = 0; i < 16; ++i) {
    int idx = tid + i * 256;
    int j = idx >> 6, k = idx & 63;
    Ws[k][j] = Wt[(size_t)j * DD + k];
  }
  __syncthreads();

  float acc[2][4] = {};
  #pragma unroll 8
  for (int k = 0; k < 64; ++k) {
    float2 af = *(const float2*)&As[k][ty * 2];
    float4 wf = *(const float4*)&Ws[k][tx * 4];
    float a[2] = {af.x, af.y};
    float w[4] = {wf.x, wf.y, wf.z, wf.w};
    #pragma unroll
    for (int i = 0; i < 2; ++i)
      #pragma unroll
      for (int j = 0; j < 4; ++j)
        acc[i][j] = fmaf(a[i], w[j], acc[i][j]);
  }
  float4 gv = *(const float4*)&g[tx * 4];
  float4 bv = *(const float4*)&bb[tx * 4];
  float4 biv = *(const float4*)&bias[tx * 4];
  float gg[4] = {gv.x, gv.y, gv.z, gv.w};
  float bbv[4] = {bv.x, bv.y, bv.z, bv.w};
  float bi[4] = {biv.x, biv.y, biv.z, biv.w};
  #pragma unroll
  for (int i = 0; i < 2; ++i) {
    int m = m0 + ty * 2 + i;
    float4 yv = *(const float4*)&y[(size_t)m * DD + tx * 4];
    float yr[4] = {yv.x, yv.y, yv.z, yv.w};
    float z[4], s = 0.f, ss = 0.f;
    #pragma unroll
    for (int j = 0; j < 4; ++j) {
      float v = acc[i][j] + bi[j] + yr[j];
      z[j] = v; s += v; ss = fmaf(v, v, ss);
    }
    #pragma unroll
    for (int off = 1; off < 16; off <<= 1) {
      s  += __shfl_xor(s, off);
      ss += __shfl_xor(ss, off);
    }
    float mean = s * 0.015625f;
    float var = ss * 0.015625f - mean * mean;
    float inv = rsqrtf(var + EPSF);
    float ov[4];
    #pragma unroll
    for (int j = 0; j < 4; ++j)
      ov[j] = (z[j] - mean) * inv * gg[j] + bbv[j];
    *(float4*)&y[(size_t)m * DD + tx * 4] = make_float4(ov[0], ov[1], ov[2], ov[3]);
    size_t yb = (size_t)m * DD + tx * 4;
    #pragma unroll
    for (int j = 0; j < 4; ++j) {
      ushort_t h = f2bf(ov[j]);
      yh[yb + j] = h;
      yl[yb + j] = f2bf(ov[j] - bf2f(h));
    }
  }
}

// ---- fused FF via split-bf16 MFMA, zero-redundancy loads ----
// 64-row m-tiles (round-9 proven config; 32-row probe regressed).
__global__ __launch_bounds__(256) void k_ff(const ushort_t* __restrict__ yh,
    const ushort_t* __restrict__ yl,
    const ushort_t* __restrict__ w1h, const ushort_t* __restrict__ w1l,
    const float* __restrict__ b1,
    const ushort_t* __restrict__ w2h, const ushort_t* __restrict__ w2l,
    float* __restrict__ pff)
{
  __shared__ ushort_t Hh[64][72];   // H[m][ff] hi bf16, stride 72 (16B align)
  __shared__ ushort_t Hl[64][72];   // H[m][ff] lo bf16
  int tid = threadIdx.x;
  int w = tid >> 6, lane = tid & 63;
  int laneR = lane & 15, laneQ = lane >> 4;
  int split = blockIdx.x;
  int m0 = blockIdx.y * 64;

  s8v a1h[4][2], a1l[4][2];
  #pragma unroll
  for (int t = 0; t < 4; ++t) {
    size_t yb = (size_t)(m0 + t * 16 + laneR) * DD + laneQ * 8;
    a1h[t][0] = *(const s8v*)(yh + yb);
    a1h[t][1] = *(const s8v*)(yh + yb + 32);
    a1l[t][0] = *(const s8v*)(yl + yb);
    a1l[t][1] = *(const s8v*)(yl + yb + 32);
  }

  f4v acc2[4];
  #pragma unroll
  for (int t = 0; t < 4; ++t) acc2[t] = (f4v){0.f, 0.f, 0.f, 0.f};

  for (int c = 0; c < FFF / FFSPLIT / 64; ++c) {
    int ff0 = split * (FFF / FFSPLIT) + c * 64;
    size_t wb1 = (size_t)(ff0 + w * 16 + laneR) * DD + laneQ * 8;
    s8v b0h = *(const s8v*)(w1h + wb1);
    s8v b0l = *(const s8v*)(w1l + wb1);
    s8v b1h_ = *(const s8v*)(w1h + wb1 + 32);
    s8v b1l_ = *(const s8v*)(w1l + wb1 + 32);
    size_t wb2 = (size_t)(w * 16 + laneR) * FFF + ff0 + laneQ * 8;
    s8v c0h = *(const s8v*)(w2h + wb2);
    s8v c0l = *(const s8v*)(w2l + wb2);
    s8v c1h = *(const s8v*)(w2h + wb2 + 32);
    s8v c1l = *(const s8v*)(w2l + wb2 + 32);
    float bj = b1[ff0 + w * 16 + laneR];

    if (c) __syncthreads();
    #pragma unroll
    for (int t = 0; t < 4; ++t) {
      f4v acc = (f4v){0.f, 0.f, 0.f, 0.f};
      acc = __builtin_amdgcn_mfma_f32_16x16x32_bf16(a1h[t][0], b0h, acc, 0, 0, 0);
      acc = __builtin_amdgcn_mfma_f32_16x16x32_bf16(a1h[t][0], b0l, acc, 0, 0, 0);
      acc = __builtin_amdgcn_mfma_f32_16x16x32_bf16(a1l[t][0], b0h, acc, 0, 0, 0);
      acc = __builtin_amdgcn_mfma_f32_16x16x32_bf16(a1h[t][1], b1h_, acc, 0, 0, 0);
      acc = __builtin_amdgcn_mfma_f32_16x16x32_bf16(a1h[t][1], b1l_, acc, 0, 0, 0);
      acc = __builtin_amdgcn_mfma_f32_16x16x32_bf16(a1l[t][1], b1h_, acc, 0, 0, 0);
      #pragma unroll
      for (int r = 0; r < 4; ++r) {
        float v = fmaxf(acc[r] + bj, 0.f);
        ushort_t hb = f2bf(v);
        int rr = t * 16 + laneQ * 4 + r, cc = w * 16 + laneR;
        Hh[rr][cc] = hb;
        Hl[rr][cc] = f2bf(v - bf2f(hb));
      }
    }
    __syncthreads();
    #pragma unroll
    for (int t = 0; t < 4; ++t) {
      s8v a2h[2], a2l[2];
      #pragma unroll
      for (int half = 0; half < 2; ++half) {
        a2h[half] = *(const s8v*)&Hh[t * 16 + laneR][half * 32 + laneQ * 8];
        a2l[half] = *(const s8v*)&Hl[t * 16 + laneR][half * 32 + laneQ * 8];
      }
      acc2[t] = __builtin_amdgcn_mfma_f32_16x16x32_bf16(a2h[0], c0h, acc2[t], 0, 0, 0);
      acc2[t] = __builtin_amdgcn_mfma_f32_16x16x32_bf16(a2h[0], c0l, acc2[t], 0, 0, 0);
      acc2[t] = __builtin_amdgcn_mfma_f32_16x16x32_bf16(a2l[0], c0h, acc2[t], 0, 0, 0);
      acc2[t] = __builtin_amdgcn_mfma_f32_16x16x32_bf16(a2h[1], c1h, acc2[t], 0, 0, 0);
      acc2[t] = __builtin_amdgcn_mfma_f32_16x16x32_bf16(a2h[1], c1l, acc2[t], 0, 0, 0);
      acc2[t] = __builtin_amdgcn_mfma_f32_16x16x32_bf16(a2l[1], c1h, acc2[t], 0, 0, 0);
    }
  }
  #pragma unroll
  for (int t = 0; t < 4; ++t) {
    #pragma unroll
    for (int r = 0; r < 4; ++r) {
      int m = m0 + t * 16 + laneQ * 4 + r;
      pff[((size_t)split * NROW + m) * DD + w * 16 + laneR] = acc2[t][r];
    }
  }
}

// ---- MFMA flash attention (split-K): QK^T and PV on matrix cores ----
// Swapped QK^T (lane-local q-row) + in-register P->PV handoff (k-bijection
// applied to both PV operands). qkv is HEAD-MAJOR [plane][b][head][s][8].
// exp2 via raw v_exp_f32 (__builtin_amdgcn_exp2f) -- drops the OCML precise
// path's range-check instructions from the per-chunk VALU critical chain.
__global__ __launch_bounds__(256) void k_attn(const float* __restrict__ qkv,
    float* __restrict__ pl, float* __restrict__ pacc)
{
  __shared__ ushort_t Kb[KB][8];       // bf16 K rows: Kb[key][d]
  __shared__ ushort_t Vt[8][KB + 8];   // bf16 V transposed: Vt[d][key]
  int bh = blockIdx.x; int b = bh >> 3; int hh = bh & 7;
  int qt = blockIdx.y, sp = blockIdx.z;
  int tid = threadIdx.x;

  const float* kbase = qkv + (((size_t)BB + b) * NHH + hh) * (SS * 8)
                           + (size_t)(sp * KB) * 8;
  const float* vbase = qkv + (((size_t)2 * BB + b) * NHH + hh) * (SS * 8)
                           + (size_t)(sp * KB) * 8;
  for (int r = tid; r < KB; r += 256) {
    const float* ksrc = kbase + (size_t)r * 8;
    float4 k0 = *(const float4*)ksrc;
    float4 k1 = *(const float4*)(ksrc + 4);
    ushort_t kh[8] = {f2bf(k0.x), f2bf(k0.y), f2bf(k0.z), f2bf(k0.w),
                      f2bf(k1.x), f2bf(k1.y), f2bf(k1.z), f2bf(k1.w)};
    *(uint4*)&Kb[r][0] = *(const uint4*)kh;
    const float* vsrc = vbase + (size_t)r * 8;
    float4 v0 = *(const float4*)vsrc;
    float4 v1 = *(const float4*)(vsrc + 4);
    Vt[0][r] = f2bf(v0.x); Vt[1][r] = f2bf(v0.y);
    Vt[2][r] = f2bf(v0.z); Vt[3][r] = f2bf(v0.w);
    Vt[4][r] = f2bf(v1.x); Vt[5][r] = f2bf(v1.y);
    Vt[6][r] = f2bf(v1.z); Vt[7][r] = f2bf(v1.w);
  }
  __syncthreads();

  int w = tid >> 6, lane = tid & 63;
  int n = lane & 15, quad = lane >> 4;
  const float scq = 0.51006972783f;    // log2(e) / sqrt(8)
  const s8v zero8 = (s8v){0, 0, 0, 0, 0, 0, 0, 0};
  const f4v zero4 = (f4v){0.f, 0.f, 0.f, 0.f};

  s8v aq = zero8;
  if (quad == 0) {
    const float* qp = qkv + ((size_t)b * NHH + hh) * (SS * 8)
                          + (size_t)(qt * 64 + w * 16 + n) * 8;
    float4 q0 = *(const float4*)qp;
    float4 q1 = *(const float4*)(qp + 4);
    aq[0] = (short)f2bf(q0.x * scq); aq[1] = (short)f2bf(q0.y * scq);
    aq[2] = (short)f2bf(q0.z * scq); aq[3] = (short)f2bf(q0.w * scq);
    aq[4] = (short)f2bf(q1.x * scq); aq[5] = (short)f2bf(q1.y * scq);
    aq[6] = (short)f2bf(q1.z * scq); aq[7] = (short)f2bf(q1.w * scq);
  }

  f4v accO = zero4;
  float l = 0.f;

  #pragma unroll 2
  for (int ck = 0; ck < KB; ck += 32) {
    s8v ak0 = zero8, ak1 = zero8;
    if (quad == 0) {
      ak0 = *(const s8v*)&Kb[ck + n][0];
      ak1 = *(const s8v*)&Kb[ck + 16 + n][0];
    }
    // swapped operands: S[key=ck+4q+r][qrow=n] in c0, S[key=ck+16+4q+r] in c1
    f4v c0 = __builtin_amdgcn_mfma_f32_16x16x32_bf16(ak0, aq, zero4, 0, 0, 0);
    f4v c1 = __builtin_amdgcn_mfma_f32_16x16x32_bf16(ak1, aq, zero4, 0, 0, 0);
    float p0[4], p1[4];
    #pragma unroll
    for (int r = 0; r < 4; ++r) { p0[r] = __builtin_amdgcn_exp2f(c0[r]); l += p0[r]; }
    #pragma unroll
    for (int r = 0; r < 4; ++r) { p1[r] = __builtin_amdgcn_exp2f(c1[r]); l += p1[r]; }
    unsigned u0, u1, v0, v1;
    asm("v_cvt_pk_bf16_f32 %0, %1, %2" : "=v"(u0) : "v"(p0[0]), "v"(p0[1]));
    asm("v_cvt_pk_bf16_f32 %0, %1, %2" : "=v"(u1) : "v"(p0[2]), "v"(p0[3]));
    asm("v_cvt_pk_bf16_f32 %0, %1, %2" : "=v"(v0) : "v"(p1[0]), "v"(p1[1]));
    asm("v_cvt_pk_bf16_f32 %0, %1, %2" : "=v"(v1) : "v"(p1[2]), "v"(p1[3]));
    // A-fragment: this lane's own P values, keys {4q..4q+3, 16+4q..16+4q+3}
    union { uint4 u; s8v s; } ca;
    ca.u = make_uint4(u0, u1, v0, v1);
    // B-fragment: V at the SAME permuted key order (two b64 reads, 8B-aligned)
    const ushort_t* vp = &Vt[n & 7][ck + quad * 4];
    uint2 bv0 = *(const uint2*)vp;
    uint2 bv1 = *(const uint2*)(vp + 16);
    union { uint4 u; s8v s; } cb;
    cb.u = make_uint4(bv0.x, bv0.y, bv1.x, bv1.y);
    accO = __builtin_amdgcn_mfma_f32_16x16x32_bf16(ca.s, cb.s, accO, 0, 0, 0);
  }

  // l[q=n] is per-lane: reduce across the 4 quads
  l += __shfl_xor(l, 16);
  l += __shfl_xor(l, 32);
  int qbase0 = qt * 64 + w * 16;
  size_t pbase0 = ((size_t)sp * 16 + bh) * SS + qbase0;
  if (quad == 0) pl[pbase0 + n] = l;
  size_t pbase = pbase0 + quad * 4;
  if (n < 8) {
    #pragma unroll
    for (int r = 0; r < 4; ++r)
      pacc[(pbase + r) * 8 + n] = accO[r];
  }
}

// ---- fused: softmax over 441 logits -> kernel_out + 3-channel gather ----
__global__ __launch_bounds__(256) void k_softgather(const float* __restrict__ logits,
    const float* __restrict__ x, float* __restrict__ kout, float* __restrict__ out)
{
  __shared__ float red[8];
  __shared__ float gred[3][4];
  int row = blockIdx.x;               // b*S + s
  int b = row / SS, s = row % SS;
  int h = s / WW, w = s % WW;
  const float* lp = logits + (size_t)row * PP;
  int t = threadIdx.x;
  float v0 = (t < PP) ? lp[t] : -1e30f;
  float v1 = (t + 256 < PP) ? lp[t + 256] : -1e30f;
  float mx = fmaxf(v0, v1);
  #pragma unroll
  for (int off = 32; off; off >>= 1) mx = fmaxf(mx, __shfl_xor(mx, off));
  if ((t & 63) == 0) red[t >> 6] = mx;
  __syncthreads();
  mx = fmaxf(fmaxf(red[0], red[1]), fmaxf(red[2], red[3]));
  float e0 = (t < PP) ? __expf(v0 - mx) : 0.f;
  float e1 = (t + 256 < PP) ? __expf(v1 - mx) : 0.f;
  float sm = e0 + e1;
  #pragma unroll
  for (int off = 32; off; off >>= 1) sm += __shfl_xor(sm, off);
  if ((t & 63) == 0) red[4 + (t >> 6)] = sm;
  __syncthreads();
  float inv = 1.f / (red[4] + red[5] + red[6] + red[7]);
  float p0 = e0 * inv, p1 = e1 * inv;
  if (t < PP)       kout[(size_t)(b * PP + t) * SS + s] = p0;
  if (t + 256 < PP) kout[(size_t)(b * PP + t + 256) * SS + s] = p1;

  int kr0 = t / KS, kc0 = t - kr0 * KS;
  int t1 = t + 256;
  int kr1 = t1 / KS, kc1 = t1 - kr1 * KS;
  int ih0 = h + kr0 - 10; ih0 = (ih0 < 0) ? -ih0 : (ih0 > 47 ? 94 - ih0 : ih0);
  int iw0 = w + kc0 - 10; iw0 = (iw0 < 0) ? -iw0 : (iw0 > 47 ? 94 - iw0 : iw0);
  int ih1 = h + kr1 - 10; ih1 = (ih1 < 0) ? -ih1 : (ih1 > 47 ? 94 - ih1 : ih1);
  int iw1 = w + kc1 - 10; iw1 = (iw1 < 0) ? -iw1 : (iw1 > 47 ? 94 - iw1 : iw1);
  float acc[3];
  #pragma unroll
  for (int c = 0; c < 3; ++c) {
    const float* xb = x + (size_t)(b * CC + c) * HH * WW;
    float a = 0.f;
    if (t < PP)  a = p0 * xb[ih0 * WW + iw0];
    if (t1 < PP) a = fmaf(p1, xb[ih1 * WW + iw1], a);
    acc[c] = a;
  }
  #pragma unroll
  for (int c = 0; c < 3; ++c) {
    #pragma unroll
    for (int off = 32; off; off >>= 1) acc[c] += __shfl_xor(acc[c], off);
  }
  if ((t & 63) == 0) {
    gred[0][t >> 6] = acc[0];
    gred[1][t >> 6] = acc[1];
    gred[2][t >> 6] = acc[2];
  }
  __syncthreads();
  if (t < 3) {
    float r = gred[t][0] + gred[t][1] + gred[t][2] + gred[t][3];
    out[((size_t)(b * CC + t) * HH + h) * WW + w] = r;
  }
}

extern "C" void kernel_launch(void* const* d_in, const int* in_sizes, int n_in,
                              void* d_out, int out_size, void* d_ws, size_t ws_size,
                              hipStream_t stream)
{
  (void)in_sizes; (void)n_in; (void)out_size; (void)ws_size;
  const float* x       = (const float*)d_in[0];
  const float* conv1_w = (const float*)d_in[1];
  const float* conv1_b = (const float*)d_in[2];
  const float* bn_g    = (const float*)d_in[3];
  const float* bn_b    = (const float*)d_in[4];
  const float* bn_m    = (const float*)d_in[5];
  const float* bn_v    = (const float*)d_in[6];
  const float* w_in    = (const float*)d_in[7];
  const float* b_in    = (const float*)d_in[8];
  const float* w_out   = (const float*)d_in[9];
  const float* b_out   = (const float*)d_in[10];
  const float* w1      = (const float*)d_in[11];
  const float* b1      = (const float*)d_in[12];
  const float* w2      = (const float*)d_in[13];
  const float* b2      = (const float*)d_in[14];
  const float* ln1g    = (const float*)d_in[15];
  const float* ln1b    = (const float*)d_in[16];
  const float* ln2g    = (const float*)d_in[17];
  const float* ln2b    = (const float*)d_in[18];
  const float* lw      = (const float*)d_in[19];
  const float* lb      = (const float*)d_in[20];

  // workspace: ~42.8 MiB (identical layout to round-9 passing kernel)
  float* yA   = (float*)d_ws;        // 294912 (layer y, even layers)
  float* qkv  = yA + 294912;         // 884736 (head-major [plane][b][h][s][8])
  float* yB   = qkv + 884736;        // 294912 (layer y, odd layers)
  float* sc   = yB + 294912;         // union region: 4718592 floats
  float* pacc = sc;                  // attn acc partials: 4*16*2304*8 = 1179648
  float* pff  = sc;                  // FF partials: 8*4608*64 = 2359296
  float* pl   = sc + 4718592;        // attn l partials: 4*16*2304 = 147456
  ushort_t* yh  = (ushort_t*)(pl + 589824);
  ushort_t* yl  = (ushort_t*)(pl + 589824 + 147456);
  ushort_t* w1h = (ushort_t*)(pl + 589824 + 294912);
  ushort_t* w1l = (ushort_t*)(pl + 589824 + 294912 + 524288);
  ushort_t* w2h = (ushort_t*)(pl + 589824 + 294912 + 1048576);
  ushort_t* w2l = (ushort_t*)(pl + 589824 + 294912 + 1572864);
  float* logits = pl + 589824 + 294912 + 2097152;   // 2032128 floats

  float* ybuf[2] = {yA, yB};

  float* out0 = (float*)d_out;
  float* kout = out0 + (size_t)BB * CC * HH * WW;

  k_split2<<<8192, 256, 0, stream>>>(w1, w2, w1h, w1l, w2h, w2l);
  k_conv<<<1152, 256, 0, stream>>>(x, conv1_w, conv1_b, bn_g, bn_b, bn_m, bn_v, yA);

  for (int l = 0; l < NLL; ++l) {
    float* ycur = ybuf[l & 1];
    if (l == 0)
      k_gemm32f<<<dim3(144, 3), 256, 0, stream>>>(yA, w_in, b_in, qkv, 192,
          nullptr, nullptr, nullptr, nullptr, yA);
    else
      // reads prev-layer y, writes LN2 output into ycur (different buffer -> no race)
      k_gemm32f<<<dim3(144, 3), 256, 0, stream>>>(ybuf[(l - 1) & 1],
          w_in + (size_t)l * 192 * 64, b_in + l * 192, qkv, 192,
          pff, b2 + (l - 1) * DD, ln2g + (l - 1) * 64, ln2b + (l - 1) * 64, ycur);
    k_attn<<<dim3(16, 36, KSPLIT), 256, 0, stream>>>(qkv, pl, pacc);
    k_oproj_ln<<<144, 256, 0, stream>>>(pl, pacc, w_out + (size_t)l * 64 * 64,
        b_out + l * 64, ycur, ln1g + l * 64, ln1b + l * 64, yh, yl);
    k_ff<<<dim3(FFSPLIT, 72), 256, 0, stream>>>(yh, yl,
        w1h + (size_t)l * FFF * DD, w1l + (size_t)l * FFF * DD, b1 + (size_t)l * FFF,
        w2h + (size_t)l * FFF * DD, w2l + (size_t)l * FFF * DD, pff);
  }

  // final: reduce layer-7 FF + LN2 once, then logits GEMM without
  // the 7x-redundant fused prologue
  k_ffred<<<1152, 256, 0, stream>>>(ybuf[1], pff, b2 + 7 * DD,
      ln2g + 7 * 64, ln2b + 7 * 64, ybuf[0]);
  k_gemm32f<<<dim3(144, 7), 256, 0, stream>>>(ybuf[0], lw, lb, logits, 441,
      nullptr, nullptr, nullptr, nullptr, ybuf[1]);
  k_softgather<<<NROW, 256, 0, stream>>>(logits, x, kout, out0);
}